// Round 5
// baseline (260.543 us; speedup 1.0000x reference)
//
#include <hip/hip_runtime.h>
#include <cstddef>

// StreamingISTFT fully fused: staged denorm -> FFT32(k2) -> LDS -> FFT32(k1)
// -> window -> LDS frame tile -> overlap-add -> coalesced stores.
// B=8, F=1024(+Nyquist), T=2048, HOP=512, L=2048.
// irfft(2048) = complex IFFT(1024) (real-packing); IFFT(1024) = 32x32 four-step.
//
// R8:  XCD-aware remap: FETCH 446->67 MB, kernel 165->97 us.
// R10: frame-split OLA (6-reg carry), no spill.
// R11: LDS-staged input (float4, denorm once, chunk pipeline): 100->85 us,
//      FETCH 80->66 MB (ideal). VALUBusy still 41%, occupancy 26% ->
//      latency-bound: only ~2-4 blocks/CU to cover a 12-phase serial chain.
// R12: quarter-split ALL LDS tenants -> 17408 B/block => 5-6 blocks/CU
//      (static 63-75% occupancy, was 50% static / 26% measured).
//      - staging: 4 chunks x (258 rows: k2-octet + mirror octet + 1-2 extra
//        rows for the q=0 mirror boundary), load(c+1) issued before compute(c).
//      - X transpose: 4 r-octets; all threads write octet p, wave p reads.
//      - F tile: 4 two-frame phases; rolling 6-reg OLA carry
//        (phase p stores rel {2p,2p+1} (+8..10 at p=3), carries {2p+2..2p+4}).
//      Barriers 11 -> ~24, amortized by 5-6x block residency.

#define TDIM 2048
#define FDIM 1024
#define TT 8                    // t-columns per block
#define NTOT (512 * 2048)       // output samples per batch
#define SPL 2064                // staging plane stride (258 rows * 8)
#define XPL 2176                // X quarter plane stride (32*68)
#define FST 2054                // frame tile row stride (even: float2 writes)

static constexpr int kBREV[32] = {0,16,8,24,4,20,12,28,2,18,10,26,6,22,14,30,
                                  1,17,9,25,5,21,13,29,3,19,11,27,7,23,15,31};
// e^{+2*pi*i*r/32}, r=0..15 (inverse-transform sign)
static constexpr float kTR[16] = {
  1.0f, 0.98078528040323044f, 0.92387953251128674f, 0.83146961230254524f,
  0.70710678118654757f, 0.55557023301960218f, 0.38268343236508978f, 0.19509032201612825f,
  0.0f, -0.19509032201612825f, -0.38268343236508978f, -0.55557023301960218f,
  -0.70710678118654757f, -0.83146961230254524f, -0.92387953251128674f, -0.98078528040323044f};
static constexpr float kTI[16] = {
  0.0f, 0.19509032201612825f, 0.38268343236508978f, 0.55557023301960218f,
  0.70710678118654757f, 0.83146961230254524f, 0.92387953251128674f, 0.98078528040323044f,
  1.0f, 0.98078528040323044f, 0.92387953251128674f, 0.83146961230254524f,
  0.70710678118654757f, 0.55557023301960218f, 0.38268343236508978f, 0.19509032201612825f};
// 64th roots of unity: kCC[k2]=cos(2*pi*k2/64), kSS[k2]=sin(2*pi*k2/64)
static constexpr float kCC[32] = {
  1.0f, 0.99518472667219693f, 0.98078528040323044f, 0.95694033573220882f,
  0.92387953251128674f, 0.88192126434835505f, 0.83146961230254524f, 0.77301045336273699f,
  0.70710678118654757f, 0.63439328416364549f, 0.55557023301960218f, 0.47139673682599764f,
  0.38268343236508978f, 0.29028467725446233f, 0.19509032201612825f, 0.098017140329560604f,
  0.0f, -0.098017140329560604f, -0.19509032201612825f, -0.29028467725446233f,
  -0.38268343236508978f, -0.47139673682599764f, -0.55557023301960218f, -0.63439328416364549f,
  -0.70710678118654757f, -0.77301045336273699f, -0.83146961230254524f, -0.88192126434835505f,
  -0.92387953251128674f, -0.95694033573220882f, -0.98078528040323044f, -0.99518472667219693f};
static constexpr float kSS[32] = {
  0.0f, 0.098017140329560604f, 0.19509032201612825f, 0.29028467725446233f,
  0.38268343236508978f, 0.47139673682599764f, 0.55557023301960218f, 0.63439328416364549f,
  0.70710678118654757f, 0.77301045336273699f, 0.83146961230254524f, 0.88192126434835505f,
  0.92387953251128674f, 0.95694033573220882f, 0.98078528040323044f, 0.99518472667219693f,
  1.0f, 0.99518472667219693f, 0.98078528040323044f, 0.95694033573220882f,
  0.92387953251128674f, 0.88192126434835505f, 0.83146961230254524f, 0.77301045336273699f,
  0.70710678118654757f, 0.63439328416364549f, 0.55557023301960218f, 0.47139673682599764f,
  0.38268343236508978f, 0.29028467725446233f, 0.19509032201612825f, 0.098017140329560604f};

template <int H>
__device__ __forceinline__ void fft32_stage(float ar[32], float ai[32]) {
  constexpr int TSTEP = 16 / H;
  #pragma unroll
  for (int g = 0; g < 32; g += 2 * H) {
    #pragma unroll
    for (int j = 0; j < H; ++j) {
      const float twr = kTR[j * TSTEP];
      const float twi = kTI[j * TSTEP];
      const int i0 = g + j, i1 = i0 + H;
      const float tr = twr * ar[i1] - twi * ai[i1];
      const float ti = twr * ai[i1] + twi * ar[i1];
      ar[i1] = ar[i0] - tr; ai[i1] = ai[i0] - ti;
      ar[i0] += tr;         ai[i0] += ti;
    }
  }
}

__device__ __forceinline__ void ifft32_core(float ar[32], float ai[32]) {
  fft32_stage<1>(ar, ai);
  fft32_stage<2>(ar, ai);
  fft32_stage<4>(ar, ai);
  fft32_stage<8>(ar, ai);
  fft32_stage<16>(ar, ai);
}

// |v|^(2*PE) * KS via native v_log_f32 + v_exp_f32. v=0 -> 0: ok.
__device__ __forceinline__ float pow_gain(float v, float PE, float KS) {
  return KS * __builtin_amdgcn_exp2f(PE * __builtin_amdgcn_logf(v));
}

__device__ __forceinline__ void denorm4(float4& r, float4& i, float PE, float KS) {
  float g;
  g = pow_gain(r.x * r.x + i.x * i.x, PE, KS); r.x *= g; i.x *= g;
  g = pow_gain(r.y * r.y + i.y * i.y, PE, KS); r.y *= g; i.y *= g;
  g = pow_gain(r.z * r.z + i.z * i.z, PE, KS); r.z *= g; i.z *= g;
  g = pow_gain(r.w * r.w + i.w * i.w, PE, KS); r.w *= g; i.w *= g;
}

// Chunk C covers k2-octet K(C) = {4C..4C+3} u {28-4C..31-4C} (C=3: {12..19}),
// symmetric under k2 -> 31-k2 so Hermitian mirrors (q>0) stay in-chunk.
// Main slots s in [0,256): row = 32*k2(C, s>>5) + (s&31). Extra slots 256(,257)
// hold the q=0 mirror-boundary rows.
template <int C>
__device__ __forceinline__ int chunk_k2(int u) {
  return (C == 3) ? 12 + u : (u < 4 ? 4 * C + u : 24 - 4 * C + u);
}

template <int C>
__device__ __forceinline__ void chunk_load(const float* __restrict__ re_p,
                                           const float* __restrict__ im_p,
                                           int t0, int tid,
                                           float4 re[2], float4 im[2],
                                           float4& exr, float4& exi) {
  #pragma unroll
  for (int j = 0; j < 2; ++j) {
    const int f = tid + 256 * j;        // [0,512)
    const int s = f >> 1, cg = f & 1;
    const int row = 32 * chunk_k2<C>(s >> 5) + (s & 31);
    re[j] = *(const float4*)(re_p + (size_t)row * TDIM + t0 + 4 * cg);
    im[j] = *(const float4*)(im_p + (size_t)row * TDIM + t0 + 4 * cg);
  }
  constexpr int NE = (C == 1 || C == 2) ? 2 : 1;
  if (tid < 2 * NE) {
    const int er = tid >> 1, cg = tid & 1;
    const int row = (C == 0) ? 128
                  : (C == 1) ? (er ? 896 : 256)
                  : (C == 2) ? (er ? 768 : 384) : 640;
    exr = *(const float4*)(re_p + (size_t)row * TDIM + t0 + 4 * cg);
    exi = *(const float4*)(im_p + (size_t)row * TDIM + t0 + 4 * cg);
  }
}

template <int C>
__device__ __forceinline__ void chunk_stage(float* __restrict__ Sre,
                                            float* __restrict__ Sim, int tid,
                                            float4 re[2], float4 im[2],
                                            float4& exr, float4& exi,
                                            float PE, float KS) {
  #pragma unroll
  for (int j = 0; j < 2; ++j) {
    const int f = tid + 256 * j;
    denorm4(re[j], im[j], PE, KS);
    *(float4*)(Sre + 4 * f) = re[j];    // 4f = slot*8 + 4*cg
    *(float4*)(Sim + 4 * f) = im[j];
  }
  constexpr int NE = (C == 1 || C == 2) ? 2 : 1;
  if (tid < 2 * NE) {
    denorm4(exr, exi, PE, KS);
    *(float4*)(Sre + 2048 + 4 * tid) = exr;   // slots 256,257
    *(float4*)(Sim + 2048 + 4 * tid) = exi;
  }
}

// q=0 mirror slot exceptions: u==0 -> E0, u==4 -> E4 (else 32*(8-u)).
template <int C>
__device__ __forceinline__ void chunk_compute(const float* __restrict__ Sre,
                                              const float* __restrict__ Sim,
                                              int q, int tl, float wc, float ws,
                                              float ar[32], float ai[32]) {
  constexpr int E0 = (C == 0) ? 0 : (C == 3) ? 256 : 257;
  constexpr int E4 = (C == 3) ? 128 : 256;
  #pragma unroll
  for (int u = 0; u < 8; ++u) {
    const int k2 = chunk_k2<C>(u);      // compile-time (u literal)
    const int slot = q + 32 * u;
    const int slotm_z = (u == 0) ? E0 : (u == 4) ? E4 : 32 * (8 - u);
    const int slotm_p = (32 - q) + 32 * (7 - u);
    const int slotm = (q == 0) ? slotm_z : slotm_p;

    const float s1r = Sre[slot * 8 + tl],  s1i = Sim[slot * 8 + tl];
    const float s2r = Sre[slotm * 8 + tl], s2i = Sim[slotm * 8 + tl];
    // W[k] = (S1 + conj(S2)) + i*T*(S1 - conj(S2)),  T = e^{i pi k/1024}
    // T = e^{i pi q/1024} * e^{i pi k2/32}  (constant tables, 4 FMA)
    const float cs = wc * kCC[k2] - ws * kSS[k2];
    const float sn = ws * kCC[k2] + wc * kSS[k2];
    const float Pre = s1r + s2r, Pim = s1i - s2i;
    const float Qre = s1r - s2r, Qim = s1i + s2i;
    const float uu = cs * Qim + sn * Qre;
    const float vv = cs * Qre - sn * Qim;
    float wr = Pre - uu, wi = Pim + vv;
    if (C == 0 && u == 0 && q == 0) { wr = s1r; wi = s1r; }  // DC/Nyquist
    ar[kBREV[k2]] = wr; ai[kBREV[k2]] = wi;
  }
}

// X quarter layout: XQ(t, k1, rh) = k1*68 + rh*8 + t, rh in [0,8). Writes:
// bank = (4q+8rh+tl) -> 2-way (free). Reads: bank = (4k1+8j+tl) -> 2-way.
#define XQ(t, k1, rh) ((k1) * 68 + (rh) * 8 + (t))

__global__ __launch_bounds__(256) void istft_fused(const float* __restrict__ in,
                                                   const float* __restrict__ invw,
                                                   float* __restrict__ out) {
  __shared__ float buf[4352];           // 17408 B, three overlapped tenants:
  float* Sre = buf;                     //  staging: [0,2064)+[2064,4128)
  float* Sim = buf + SPL;
  float* Xqr = buf;                     //  X quarter: [0,2176)+[2176,4352)
  float* Xqi = buf + XPL;
  float* Fh  = buf;                     //  frames (2): [0,4102)

  const int tid = threadIdx.x;
  const int tl  = tid & 7;              // t within tile
  const int q   = tid >> 3;             // k1 (stage 1) / r (stage 2)

  // XCD-aware remap (R8): each XCD owns 32 contiguous t-tiles of one batch.
  const int id   = blockIdx.x;          // 0..2047
  const int xcd  = id & 7;
  const int slot = id >> 3;             // 0..255
  const int b    = slot >> 5;           // 0..7
  const int tile = xcd * 32 + (slot & 31);  // 0..255
  const int t0   = tile * TT;

  const float* re_p = in + ((size_t)b * 2 + 0) * ((size_t)FDIM * TDIM);
  const float* im_p = in + ((size_t)b * 2 + 1) * ((size_t)FDIM * TDIM);

  const float KS = (float)(exp((-1.0 / 0.65) * log(0.06)) / 2048.0);
  const float PE = 7.0f / 26.0f;

  // pack twiddle base: e^{i*pi*q/1024}
  const float aq = 3.0679615757712824e-3f * (float)q;
  const float wc = __cosf(aq), ws = __sinf(aq);

  float ar[32], ai[32];

  // ---- Stage 1: 4-chunk pipeline: stage(c) | load(c+1) | bar | compute(c) ----
  {
    float4 reA[2], imA[2], exrA, exiA;
    float4 reB[2], imB[2], exrB, exiB;
    chunk_load<0>(re_p, im_p, t0, tid, reA, imA, exrA, exiA);
    chunk_stage<0>(Sre, Sim, tid, reA, imA, exrA, exiA, PE, KS);
    chunk_load<1>(re_p, im_p, t0, tid, reB, imB, exrB, exiB);
    __syncthreads();
    chunk_compute<0>(Sre, Sim, q, tl, wc, ws, ar, ai);
    __syncthreads();
    chunk_stage<1>(Sre, Sim, tid, reB, imB, exrB, exiB, PE, KS);
    chunk_load<2>(re_p, im_p, t0, tid, reA, imA, exrA, exiA);
    __syncthreads();
    chunk_compute<1>(Sre, Sim, q, tl, wc, ws, ar, ai);
    __syncthreads();
    chunk_stage<2>(Sre, Sim, tid, reA, imA, exrA, exiA, PE, KS);
    chunk_load<3>(re_p, im_p, t0, tid, reB, imB, exrB, exiB);
    __syncthreads();
    chunk_compute<2>(Sre, Sim, q, tl, wc, ws, ar, ai);
    __syncthreads();
    chunk_stage<3>(Sre, Sim, tid, reB, imB, exrB, exiB, PE, KS);
    __syncthreads();
    chunk_compute<3>(Sre, Sim, q, tl, wc, ws, ar, ai);
    __syncthreads();                    // staging dead; X may overwrite buf
  }

  // ---- FFT32 over k2 ----
  ifft32_core(ar, ai);

  // ---- Transpose through quarter X (4 r-octets) ----
  float zr[32], zi[32];
  #pragma unroll
  for (int p = 0; p < 4; ++p) {
    #pragma unroll
    for (int rr = 0; rr < 8; ++rr) {    // all threads write octet p
      const int r = 8 * p + rr;         // twiddle e^{2 pi i q r/1024}
      const float ang = 6.1359231515425649e-3f * (float)(q * r);
      const float sn = __sinf(ang), cs = __cosf(ang);
      Xqr[XQ(tl, q, rr)] = cs * ar[r] - sn * ai[r];
      Xqi[XQ(tl, q, rr)] = cs * ai[r] + sn * ar[r];
    }
    __syncthreads();
    if ((q >> 3) == p) {                // wave p reads its stage-2 input
      const int qq = q & 7;
      #pragma unroll
      for (int i = 0; i < 32; ++i) {    // bit-reversed k1 load order
        zr[i] = Xqr[XQ(tl, kBREV[i], qq)];
        zi[i] = Xqi[XQ(tl, kBREV[i], qq)];
      }
    }
    __syncthreads();                    // p<3: before overwrite; p=3: before F
  }

  // ---- Stage 2: FFT32 over k1 ----
  ifft32_core(zr, zi);

  // ---- 4-phase frame tile + rolling-carry OLA ----
  // frames[tl][l], l = 2*(q+32s)+{0,1}. Phase p holds frames {2p, 2p+1}.
  // Phase p stores rel {2p,2p+1} (+{8,9,10} at p=3); carries rel {2p+2..2p+4}.
  float* ob = out + (size_t)b * NTOT;
  float carry[2][3];

  #pragma unroll
  for (int p = 0; p < 4; ++p) {
    if ((tl >> 1) == p) {               // 64 threads write frames 2p, 2p+1
      const int row = tl & 1;
      #pragma unroll
      for (int s = 0; s < 32; ++s) {
        const int l0 = 2 * q + 64 * s;
        const float2 w2 = *(const float2*)(invw + l0);
        float2 fv; fv.x = zr[s] * w2.x; fv.y = zi[s] * w2.y;
        *(float2*)(Fh + row * FST + l0) = fv;
      }
    }
    __syncthreads();
    #pragma unroll
    for (int half = 0; half < 2; ++half) {
      const int j = tid + 256 * half;   // lanes j-consecutive -> coalesced
      #pragma unroll
      for (int rel = 2 * p; rel < 2 * p + 5 && rel < 11; ++rel) {
        float v = (p > 0 && rel - 2 * p < 3) ? carry[half][rel - 2 * p] : 0.0f;
        #pragma unroll
        for (int c = 0; c < 4; ++c) {
          const int tt = rel - c;
          if (tt == 2 * p || tt == 2 * p + 1)
            v += Fh[(tt - 2 * p) * FST + j + 512 * c];
        }
        if (rel <= 2 * p + 1 || p == 3) {           // complete -> store
          const int tp = t0 + rel;
          if (rel < 8 || tp <= 2047) {
            const int n = tp * 512 + j;
            if (rel >= 3 && rel <= 7) ob[n] = v;    // all 4 in-block
            else atomicAdd(&ob[n], v);              // tile boundary
          }
        } else {
          carry[half][rel - (2 * p + 2)] = v;       // roll forward
        }
      }
    }
    if (p < 3) __syncthreads();         // before next phase overwrites Fh
  }
}

extern "C" void kernel_launch(void* const* d_in, const int* in_sizes, int n_in,
                              void* d_out, int out_size, void* d_ws, size_t ws_size,
                              hipStream_t stream) {
  (void)in_sizes; (void)n_in; (void)d_ws; (void)ws_size;
  const float* in   = (const float*)d_in[0];
  const float* invw = (const float*)d_in[1];
  float* out = (float*)d_out;
  hipMemsetAsync(out, 0, (size_t)out_size * sizeof(float), stream);
  istft_fused<<<dim3(TDIM / TT * 8), 256, 0, stream>>>(in, invw, out);
}

// Round 6
// 228.411 us; speedup vs baseline: 1.1407x; 1.1407x over previous
//
#include <hip/hip_runtime.h>
#include <cstddef>

// StreamingISTFT fully fused: staged denorm -> FFT32(k2) -> LDS -> FFT32(k1)
// -> window -> LDS frame tile -> overlap-add -> coalesced stores.
// B=8, F=1024(+Nyquist), T=2048, HOP=512, L=2048.
// irfft(2048) = complex IFFT(1024) (real-packing); IFFT(1024) = 32x32 four-step.
//
// R8:  XCD-aware remap: FETCH 446->67 MB, kernel 165->97 us.
// R11: LDS-staged input, half-X transpose, 2-phase frame OLA: 85 us (best).
// R12: quarter-split everything -> 117 us REGRESSION. Occupancy is VGPR-bin
//      bound (16 waves/CU at VGPR~100), so smaller LDS bought no residency;
//      doubled barriers + 3/4-idle phases added pure stall.
// R13: R11 skeleton (half-X transpose, 2-phase OLA) + overlapped stage-1:
//      quarter-chunk staging planes (4128 fl) double-buffered inside the same
//      33.8 KB -> pipeline load(c+2) | stage(c+1,P^1) | compute(c,P), one
//      barrier per chunk (5 total in stage 1). All staging VALU + global
//      latency hidden under chunk_compute. Chunk helpers verbatim from R12
//      (correctness-proven there).

#define TDIM 2048
#define FDIM 1024
#define TT 8                    // t-columns per block
#define NTOT (512 * 2048)       // output samples per batch
#define SPL 2064                // staging plane stride (258 rows * 8)

static constexpr int kBREV[32] = {0,16,8,24,4,20,12,28,2,18,10,26,6,22,14,30,
                                  1,17,9,25,5,21,13,29,3,19,11,27,7,23,15,31};
// e^{+2*pi*i*r/32}, r=0..15 (inverse-transform sign)
static constexpr float kTR[16] = {
  1.0f, 0.98078528040323044f, 0.92387953251128674f, 0.83146961230254524f,
  0.70710678118654757f, 0.55557023301960218f, 0.38268343236508978f, 0.19509032201612825f,
  0.0f, -0.19509032201612825f, -0.38268343236508978f, -0.55557023301960218f,
  -0.70710678118654757f, -0.83146961230254524f, -0.92387953251128674f, -0.98078528040323044f};
static constexpr float kTI[16] = {
  0.0f, 0.19509032201612825f, 0.38268343236508978f, 0.55557023301960218f,
  0.70710678118654757f, 0.83146961230254524f, 0.92387953251128674f, 0.98078528040323044f,
  1.0f, 0.98078528040323044f, 0.92387953251128674f, 0.83146961230254524f,
  0.70710678118654757f, 0.55557023301960218f, 0.38268343236508978f, 0.19509032201612825f};
// 64th roots of unity: kCC[k2]=cos(2*pi*k2/64), kSS[k2]=sin(2*pi*k2/64)
static constexpr float kCC[32] = {
  1.0f, 0.99518472667219693f, 0.98078528040323044f, 0.95694033573220882f,
  0.92387953251128674f, 0.88192126434835505f, 0.83146961230254524f, 0.77301045336273699f,
  0.70710678118654757f, 0.63439328416364549f, 0.55557023301960218f, 0.47139673682599764f,
  0.38268343236508978f, 0.29028467725446233f, 0.19509032201612825f, 0.098017140329560604f,
  0.0f, -0.098017140329560604f, -0.19509032201612825f, -0.29028467725446233f,
  -0.38268343236508978f, -0.47139673682599764f, -0.55557023301960218f, -0.63439328416364549f,
  -0.70710678118654757f, -0.77301045336273699f, -0.83146961230254524f, -0.88192126434835505f,
  -0.92387953251128674f, -0.95694033573220882f, -0.98078528040323044f, -0.99518472667219693f};
static constexpr float kSS[32] = {
  0.0f, 0.098017140329560604f, 0.19509032201612825f, 0.29028467725446233f,
  0.38268343236508978f, 0.47139673682599764f, 0.55557023301960218f, 0.63439328416364549f,
  0.70710678118654757f, 0.77301045336273699f, 0.83146961230254524f, 0.88192126434835505f,
  0.92387953251128674f, 0.95694033573220882f, 0.98078528040323044f, 0.99518472667219693f,
  1.0f, 0.99518472667219693f, 0.98078528040323044f, 0.95694033573220882f,
  0.92387953251128674f, 0.88192126434835505f, 0.83146961230254524f, 0.77301045336273699f,
  0.70710678118654757f, 0.63439328416364549f, 0.55557023301960218f, 0.47139673682599764f,
  0.38268343236508978f, 0.29028467725446233f, 0.19509032201612825f, 0.098017140329560604f};

template <int H>
__device__ __forceinline__ void fft32_stage(float ar[32], float ai[32]) {
  constexpr int TSTEP = 16 / H;
  #pragma unroll
  for (int g = 0; g < 32; g += 2 * H) {
    #pragma unroll
    for (int j = 0; j < H; ++j) {
      const float twr = kTR[j * TSTEP];
      const float twi = kTI[j * TSTEP];
      const int i0 = g + j, i1 = i0 + H;
      const float tr = twr * ar[i1] - twi * ai[i1];
      const float ti = twr * ai[i1] + twi * ar[i1];
      ar[i1] = ar[i0] - tr; ai[i1] = ai[i0] - ti;
      ar[i0] += tr;         ai[i0] += ti;
    }
  }
}

__device__ __forceinline__ void ifft32_core(float ar[32], float ai[32]) {
  fft32_stage<1>(ar, ai);
  fft32_stage<2>(ar, ai);
  fft32_stage<4>(ar, ai);
  fft32_stage<8>(ar, ai);
  fft32_stage<16>(ar, ai);
}

// |v|^(2*PE) * KS via native v_log_f32 + v_exp_f32. v=0 -> 0: ok.
__device__ __forceinline__ float pow_gain(float v, float PE, float KS) {
  return KS * __builtin_amdgcn_exp2f(PE * __builtin_amdgcn_logf(v));
}

__device__ __forceinline__ void denorm4(float4& r, float4& i, float PE, float KS) {
  float g;
  g = pow_gain(r.x * r.x + i.x * i.x, PE, KS); r.x *= g; i.x *= g;
  g = pow_gain(r.y * r.y + i.y * i.y, PE, KS); r.y *= g; i.y *= g;
  g = pow_gain(r.z * r.z + i.z * i.z, PE, KS); r.z *= g; i.z *= g;
  g = pow_gain(r.w * r.w + i.w * i.w, PE, KS); r.w *= g; i.w *= g;
}

// Chunk C covers k2-octet K(C) = {4C..4C+3} u {28-4C..31-4C} (C=3: {12..19}),
// symmetric under k2 -> 31-k2 so Hermitian mirrors (q>0) stay in-chunk.
// Main slots s in [0,256): row = 32*k2(C, s>>5) + (s&31). Extra slots 256(,257)
// hold the q=0 mirror-boundary rows. (Verbatim from R12 -- proven correct.)
template <int C>
__device__ __forceinline__ int chunk_k2(int u) {
  return (C == 3) ? 12 + u : (u < 4 ? 4 * C + u : 24 - 4 * C + u);
}

template <int C>
__device__ __forceinline__ void chunk_load(const float* __restrict__ re_p,
                                           const float* __restrict__ im_p,
                                           int t0, int tid,
                                           float4 re[2], float4 im[2],
                                           float4& exr, float4& exi) {
  #pragma unroll
  for (int j = 0; j < 2; ++j) {
    const int f = tid + 256 * j;        // [0,512)
    const int s = f >> 1, cg = f & 1;
    const int row = 32 * chunk_k2<C>(s >> 5) + (s & 31);
    re[j] = *(const float4*)(re_p + (size_t)row * TDIM + t0 + 4 * cg);
    im[j] = *(const float4*)(im_p + (size_t)row * TDIM + t0 + 4 * cg);
  }
  constexpr int NE = (C == 1 || C == 2) ? 2 : 1;
  if (tid < 2 * NE) {
    const int er = tid >> 1, cg = tid & 1;
    const int row = (C == 0) ? 128
                  : (C == 1) ? (er ? 896 : 256)
                  : (C == 2) ? (er ? 768 : 384) : 640;
    exr = *(const float4*)(re_p + (size_t)row * TDIM + t0 + 4 * cg);
    exi = *(const float4*)(im_p + (size_t)row * TDIM + t0 + 4 * cg);
  }
}

template <int C>
__device__ __forceinline__ void chunk_stage(float* __restrict__ Sre,
                                            float* __restrict__ Sim, int tid,
                                            float4 re[2], float4 im[2],
                                            float4& exr, float4& exi,
                                            float PE, float KS) {
  #pragma unroll
  for (int j = 0; j < 2; ++j) {
    const int f = tid + 256 * j;
    denorm4(re[j], im[j], PE, KS);
    *(float4*)(Sre + 4 * f) = re[j];    // 4f = slot*8 + 4*cg
    *(float4*)(Sim + 4 * f) = im[j];
  }
  constexpr int NE = (C == 1 || C == 2) ? 2 : 1;
  if (tid < 2 * NE) {
    denorm4(exr, exi, PE, KS);
    *(float4*)(Sre + 2048 + 4 * tid) = exr;   // slots 256,257
    *(float4*)(Sim + 2048 + 4 * tid) = exi;
  }
}

// q=0 mirror slot exceptions: u==0 -> E0, u==4 -> E4 (else 32*(8-u)).
template <int C>
__device__ __forceinline__ void chunk_compute(const float* __restrict__ Sre,
                                              const float* __restrict__ Sim,
                                              int q, int tl, float wc, float ws,
                                              float ar[32], float ai[32]) {
  constexpr int E0 = (C == 0) ? 0 : (C == 3) ? 256 : 257;
  constexpr int E4 = (C == 3) ? 128 : 256;
  #pragma unroll
  for (int u = 0; u < 8; ++u) {
    const int k2 = chunk_k2<C>(u);      // compile-time (u literal)
    const int slot = q + 32 * u;
    const int slotm_z = (u == 0) ? E0 : (u == 4) ? E4 : 32 * (8 - u);
    const int slotm_p = (32 - q) + 32 * (7 - u);
    const int slotm = (q == 0) ? slotm_z : slotm_p;

    const float s1r = Sre[slot * 8 + tl],  s1i = Sim[slot * 8 + tl];
    const float s2r = Sre[slotm * 8 + tl], s2i = Sim[slotm * 8 + tl];
    // W[k] = (S1 + conj(S2)) + i*T*(S1 - conj(S2)),  T = e^{i pi k/1024}
    // T = e^{i pi q/1024} * e^{i pi k2/32}  (constant tables, 4 FMA)
    const float cs = wc * kCC[k2] - ws * kSS[k2];
    const float sn = ws * kCC[k2] + wc * kSS[k2];
    const float Pre = s1r + s2r, Pim = s1i - s2i;
    const float Qre = s1r - s2r, Qim = s1i + s2i;
    const float uu = cs * Qim + sn * Qre;
    const float vv = cs * Qre - sn * Qim;
    float wr = Pre - uu, wi = Pim + vv;
    if (C == 0 && u == 0 && q == 0) { wr = s1r; wi = s1r; }  // DC/Nyquist
    ar[kBREV[k2]] = wr; ai[kBREV[k2]] = wi;
  }
}

// Half-X layout: X(t, k1, rh) = k1*132 + rh*8 + t (rh in [0,16); 132 = 16*8+4).
#define XH(t, k1, rh) ((k1) * 132 + (rh) * 8 + (t))
#define FSTR 2053               // frame tile row stride (odd -> spread banks)

__global__ __launch_bounds__(256) void istft_fused(const float* __restrict__ in,
                                                   const float* __restrict__ invw,
                                                   float* __restrict__ out) {
  __shared__ float buf[8448];           // 33.8 KB, three overlapped tenants:
                                        //  staging P0 [0,4128), P1 [4224,8352)
  float* Xhr = buf;                     //  X half:  [0,4224) + [4224,8448)
  float* Xhi = buf + 4224;
  float* Fh  = buf;                     //  frames:  [0,8212)

  const int tid = threadIdx.x;
  const int tl  = tid & 7;              // t within tile
  const int q   = tid >> 3;             // k1 (stage 1) / r (stage 2)

  // XCD-aware remap (R8): each XCD owns 32 contiguous t-tiles of one batch.
  const int id   = blockIdx.x;          // 0..2047
  const int xcd  = id & 7;
  const int slot = id >> 3;             // 0..255
  const int b    = slot >> 5;           // 0..7
  const int tile = xcd * 32 + (slot & 31);  // 0..255
  const int t0   = tile * TT;

  const float* re_p = in + ((size_t)b * 2 + 0) * ((size_t)FDIM * TDIM);
  const float* im_p = in + ((size_t)b * 2 + 1) * ((size_t)FDIM * TDIM);

  const float KS = (float)(exp((-1.0 / 0.65) * log(0.06)) / 2048.0);
  const float PE = 7.0f / 26.0f;

  // pack twiddle base: e^{i*pi*q/1024}
  const float aq = 3.0679615757712824e-3f * (float)q;
  const float wc = __cosf(aq), ws = __sinf(aq);

  float ar[32], ai[32];

  // ---- Stage 1: double-buffered quarter-chunk pipeline ----
  // phase c: load(c+2) | stage(c+1, other plane) | compute(c) | bar
  {
    float* S0r = buf;         float* S0i = buf + SPL;          // P0
    float* S1r = buf + 4224;  float* S1i = buf + 4224 + SPL;   // P1
    float4 rA[2], iA[2], exrA, exiA;
    float4 rB[2], iB[2], exrB, exiB;

    chunk_load<0>(re_p, im_p, t0, tid, rA, iA, exrA, exiA);
    chunk_stage<0>(S0r, S0i, tid, rA, iA, exrA, exiA, PE, KS);
    chunk_load<1>(re_p, im_p, t0, tid, rB, iB, exrB, exiB);
    __syncthreads();                    // P0 ready
    chunk_load<2>(re_p, im_p, t0, tid, rA, iA, exrA, exiA);
    chunk_stage<1>(S1r, S1i, tid, rB, iB, exrB, exiB, PE, KS);
    chunk_compute<0>(S0r, S0i, q, tl, wc, ws, ar, ai);
    __syncthreads();                    // P1 ready; P0 readers done
    chunk_load<3>(re_p, im_p, t0, tid, rB, iB, exrB, exiB);
    chunk_stage<2>(S0r, S0i, tid, rA, iA, exrA, exiA, PE, KS);
    chunk_compute<1>(S1r, S1i, q, tl, wc, ws, ar, ai);
    __syncthreads();                    // P0 ready; P1 readers done
    chunk_stage<3>(S1r, S1i, tid, rB, iB, exrB, exiB, PE, KS);
    chunk_compute<2>(S0r, S0i, q, tl, wc, ws, ar, ai);
    __syncthreads();                    // P1 ready
    chunk_compute<3>(S1r, S1i, q, tl, wc, ws, ar, ai);
    __syncthreads();                    // staging dead; X may overwrite buf
  }

  // ---- FFT32 over k2 ----
  ifft32_core(ar, ai);

  // ---- Transpose through half-size X (r-split, verbatim R11) ----
  float zr[32], zi[32];
  #pragma unroll
  for (int r = 0; r < 16; ++r) {        // half A, twiddle e^{2 pi i q r/1024}
    const float ang = 6.1359231515425649e-3f * (float)(q * r);
    const float sn = __sinf(ang), cs = __cosf(ang);
    Xhr[XH(tl, q, r)] = cs * ar[r] - sn * ai[r];
    Xhi[XH(tl, q, r)] = cs * ai[r] + sn * ar[r];
  }
  __syncthreads();
  if (q < 16) {                         // waves 0-1 read their stage-2 input
    #pragma unroll
    for (int i = 0; i < 32; ++i) {
      zr[i] = Xhr[XH(tl, kBREV[i], q)];
      zi[i] = Xhi[XH(tl, kBREV[i], q)];
    }
  }
  __syncthreads();
  #pragma unroll
  for (int r = 16; r < 32; ++r) {       // half B
    const float ang = 6.1359231515425649e-3f * (float)(q * r);
    const float sn = __sinf(ang), cs = __cosf(ang);
    Xhr[XH(tl, q, r - 16)] = cs * ar[r] - sn * ai[r];
    Xhi[XH(tl, q, r - 16)] = cs * ai[r] + sn * ar[r];
  }
  __syncthreads();
  if (q >= 16) {                        // waves 2-3 read their stage-2 input
    #pragma unroll
    for (int i = 0; i < 32; ++i) {
      zr[i] = Xhr[XH(tl, kBREV[i], q - 16)];
      zi[i] = Xhi[XH(tl, kBREV[i], q - 16)];
    }
  }
  __syncthreads();                      // X dead; F tile may overwrite buf

  // ---- Stage 2: FFT32 over k1 ----
  ifft32_core(zr, zi);

  // ---- Frame-split OLA: frames tt in [0,4) then [4,8) (verbatim R11) ----
  float* ob = out + (size_t)b * NTOT;
  float acc[3][2];

  if (tl < 4) {                         // F phase A: frames 0..3
    #pragma unroll
    for (int s = 0; s < 32; ++s) {
      const int l0 = 2 * q + 64 * s;
      Fh[tl * FSTR + l0]     = zr[s] * invw[l0];
      Fh[tl * FSTR + l0 + 1] = zi[s] * invw[l0 + 1];
    }
  }
  __syncthreads();
  #pragma unroll
  for (int rel = 0; rel < 7; ++rel) {   // OLA A: contributors tt in [0,4)
    #pragma unroll
    for (int half = 0; half < 2; ++half) {
      const int j = tid + 256 * half;
      float v = 0.0f;
      #pragma unroll
      for (int c = 0; c < 4; ++c) {
        const int tt = rel - c;
        if (tt >= 0 && tt < 4) v += Fh[tt * FSTR + j + 512 * c];
      }
      if (rel < 3)       atomicAdd(&ob[(t0 + rel) * 512 + j], v);  // boundary
      else if (rel == 3) ob[(t0 + rel) * 512 + j] = v;             // complete
      else               acc[rel - 4][half] = v;                   // carry 4..6
    }
  }
  __syncthreads();
  if (tl >= 4) {                        // F phase B: frames 4..7 at row tl-4
    #pragma unroll
    for (int s = 0; s < 32; ++s) {
      const int l0 = 2 * q + 64 * s;
      Fh[(tl - 4) * FSTR + l0]     = zr[s] * invw[l0];
      Fh[(tl - 4) * FSTR + l0 + 1] = zi[s] * invw[l0 + 1];
    }
  }
  __syncthreads();
  #pragma unroll
  for (int rel = 4; rel < 11; ++rel) {  // OLA B: contributors tt in [4,8)
    const int tp = t0 + rel;
    if (tp > 2047) continue;
    #pragma unroll
    for (int half = 0; half < 2; ++half) {
      const int j = tid + 256 * half;
      float v = (rel < 7) ? acc[rel - 4][half] : 0.0f;
      #pragma unroll
      for (int c = 0; c < 4; ++c) {
        const int tt = rel - c;
        if (tt >= 4 && tt < 8) v += Fh[(tt - 4) * FSTR + j + 512 * c];
      }
      const int n = tp * 512 + j;
      if (rel <= 7) ob[n] = v;          // all 4 contributors seen in-block
      else atomicAdd(&ob[n], v);        // tile boundary: 2 writers
    }
  }
}

extern "C" void kernel_launch(void* const* d_in, const int* in_sizes, int n_in,
                              void* d_out, int out_size, void* d_ws, size_t ws_size,
                              hipStream_t stream) {
  (void)in_sizes; (void)n_in; (void)d_ws; (void)ws_size;
  const float* in   = (const float*)d_in[0];
  const float* invw = (const float*)d_in[1];
  float* out = (float*)d_out;
  hipMemsetAsync(out, 0, (size_t)out_size * sizeof(float), stream);
  istft_fused<<<dim3(TDIM / TT * 8), 256, 0, stream>>>(in, invw, out);
}